// Round 5
// baseline (248.093 us; speedup 1.0000x reference)
//
#include <hip/hip_runtime.h>

// out[(b*8+r), i, j] = softmax_j( 0.125 * sum_{h, s%8==r} q[b,s,h,i]*k[b,s,h,j] )
// value input is dead (DCE'd under jit in the reference).
// q/k: [2, 16384, 8, 64] fp32; the 512 floats of (s, h=0..7, d=0..63) are contiguous.
#define NS 16384
#define BUCKETS 16

// ---------------- Stage 1: partial Gram tiles, register-only ----------------
// grid = BUCKETS*bpb blocks, 256 threads = 4 waves.
// Wave w owns the 32x32 quadrant (rows (w>>1)*32.., cols (w&1)*32..) of the
// block's 64x64 partial; each lane a 4x4 sub-tile. Operands are loaded
// directly from global (coalesced dwordx4, imm offsets over 8 heads); L1
// dedups the 2x cross-wave overlap. No LDS, no __syncthreads in the loop.
__global__ __launch_bounds__(256, 4) void gram_partial(
    const float* __restrict__ Q, const float* __restrict__ K,
    float* __restrict__ part, int bpb, int spb)
{
    const int bid    = blockIdx.x;
    const int bucket = bid / bpb;
    const int chunk  = bid % bpb;
    const int b      = bucket >> 3;
    const int r      = bucket & 7;

    const int lane = threadIdx.x & 63;
    const int wv   = threadIdx.x >> 6;
    const int ty   = lane >> 3;                  // 0..7
    const int tx   = lane & 7;                   // 0..7
    const int qcol = (wv >> 1) * 32 + ty * 4;    // C-row block (q dim i)
    const int kcol = (wv & 1) * 32 + tx * 4;     // C-col block (k dim j)

    const size_t tb = (size_t)b * ((size_t)NS * 512) + (size_t)r * 512;
    const float* qp = Q + tb + qcol;
    const float* kp = K + tb + kcol;

    float acc[4][4] = {};

    const int s0 = chunk * spb;
    for (int s = s0; s < s0 + spb; ++s) {
        const float* qb = qp + (size_t)s * 4096;   // s_hi step = 8*512 floats
        const float* kb = kp + (size_t)s * 4096;
        #pragma unroll
        for (int h = 0; h < 8; ++h) {              // 8 heads, contiguous 64-float rows
            const float4 qv = *(const float4*)(qb + h * 64);
            const float4 kv = *(const float4*)(kb + h * 64);
            const float qa[4] = {qv.x, qv.y, qv.z, qv.w};
            const float ka[4] = {kv.x, kv.y, kv.z, kv.w};
            #pragma unroll
            for (int ii = 0; ii < 4; ++ii)
                #pragma unroll
                for (int jj = 0; jj < 4; ++jj)
                    acc[ii][jj] += qa[ii] * ka[jj];
        }
    }

    // write this wave's quadrant of the block's 64x64 partial
    float* p = part + (size_t)bid * 4096
             + (size_t)((wv >> 1) * 32) * 64 + (wv & 1) * 32;
    #pragma unroll
    for (int ii = 0; ii < 4; ++ii) {
        float4 v = make_float4(acc[ii][0], acc[ii][1], acc[ii][2], acc[ii][3]);
        *(float4*)(p + (ty * 4 + ii) * 64 + tx * 4) = v;
    }
}

// ---------------- Stage 2: reduce partials + fused row softmax ----------------
// grid = 16 buckets * 64 rows = 1024 blocks, 256 threads.
// Thread (c = tid&63, sl = tid>>6): sums `slices` partials (independent,
// coalesced 256B/wave loads), LDS cross-wave reduce, in-wave softmax.
__global__ __launch_bounds__(256) void reduce_softmax(
    const float* __restrict__ part, float* __restrict__ out, int slices)
{
    const int g   = blockIdx.x >> 6;
    const int row = blockIdx.x & 63;
    const int c   = threadIdx.x & 63;
    const int sl  = threadIdx.x >> 6;

    const float* p = part + (size_t)(g * (slices * 4) + sl * slices) * 4096
                          + row * 64 + c;
    float s = 0.f;
    #pragma unroll 4
    for (int k = 0; k < slices; ++k) s += p[(size_t)k * 4096];

    __shared__ float red[4][64];
    red[sl][c] = s;
    __syncthreads();
    if (sl == 0) {
        float v = (red[0][c] + red[1][c]) + (red[2][c] + red[3][c]);
        v *= 0.125f;   // SCALE = 1/sqrt(64)
        float m = v;
        #pragma unroll
        for (int o = 32; o; o >>= 1) m = fmaxf(m, __shfl_xor(m, o));
        const float e = __expf(v - m);
        float sum = e;
        #pragma unroll
        for (int o = 32; o; o >>= 1) sum += __shfl_xor(sum, o);
        out[(size_t)g * 4096 + row * 64 + c] = e / sum;
    }
}

// ---------------- launch ----------------
extern "C" void kernel_launch(void* const* d_in, const int* in_sizes, int n_in,
                              void* d_out, int out_size, void* d_ws, size_t ws_size,
                              hipStream_t stream)
{
    const float* Q = (const float*)d_in[0];
    const float* K = (const float*)d_in[1];
    // d_in[2] (value) is dead in the reference -> never read.
    float* out  = (float*)d_out;
    float* part = (float*)d_ws;

    int bpb = 64;   // 1024 blocks, 16.7 MB workspace (fit confirmed by WRITE_SIZE)
    while ((size_t)BUCKETS * bpb * 4096 * sizeof(float) > ws_size && bpb > 4) bpb >>= 1;
    const int spb = 2048 / bpb;   // s_hi per block

    gram_partial<<<dim3(BUCKETS * bpb), dim3(256), 0, stream>>>(Q, K, part, bpb, spb);
    reduce_softmax<<<dim3(1024), dim3(256), 0, stream>>>(part, out, bpb / 4);
}